// Round 1
// baseline (900.445 us; speedup 1.0000x reference)
//
#include <hip/hip_runtime.h>
#include <math.h>

#define BB 4
#define SS 2048
#define EE 1024
#define NH 4          // kv heads
#define HD 64
#define NROW (BB*SS)  // 8192
#define PC (NH*HD)    // 256 projected cols

// ---------- Wq group-sum: Wqs[e][h][d] = sum_g Wq[e][h*4+g][d] ----------
__global__ void wq_reduce_kernel(const float* __restrict__ Wq, float* __restrict__ Wqs) {
    int idx = blockIdx.x * 256 + threadIdx.x;   // E*NH*HD = 262144 total
    int e = idx >> 8;
    int rem = idx & 255;
    int h = rem >> 6;
    int d = rem & 63;
    const float* p = Wq + (size_t)e * 1024 + h * 4 * 64 + d;
    Wqs[idx] = p[0] + p[64] + p[128] + p[192];
}

// ---------- projection: Y[NROW][256] = X[NROW][1024] @ W[1024][256], opt rope ----------
template<bool ROPE>
__global__ __launch_bounds__(256) void proj_kernel(const float* __restrict__ X,
                                                   const float* __restrict__ W,
                                                   float* __restrict__ Y) {
    __shared__ float Xs[64][17];   // [m][k]
    __shared__ float Ws[16][65];   // [k][n]
    int bm = blockIdx.x;           // 0..127
    int bn = blockIdx.y;           // 0..3
    int tid = threadIdx.x;
    int tx = tid & 15, ty = tid >> 4;
    int row0 = bm * 64, col0 = bn * 64;
    float acc[4][4] = {};
    for (int k0 = 0; k0 < EE; k0 += 16) {
        for (int i = 0; i < 4; i++) {
            int idx = i * 256 + tid;          // 0..1023
            int r = idx >> 4, c = idx & 15;
            Xs[r][c] = X[(size_t)(row0 + r) * EE + k0 + c];
        }
        for (int i = 0; i < 4; i++) {
            int idx = i * 256 + tid;
            int r = idx >> 6, c = idx & 63;
            Ws[r][c] = W[(size_t)(k0 + r) * PC + col0 + c];
        }
        __syncthreads();
        #pragma unroll
        for (int kk = 0; kk < 16; kk++) {
            float xv[4], wv[4];
            #pragma unroll
            for (int i = 0; i < 4; i++) xv[i] = Xs[ty * 4 + i][kk];
            #pragma unroll
            for (int j = 0; j < 4; j++) wv[j] = Ws[kk][tx * 4 + j];
            #pragma unroll
            for (int i = 0; i < 4; i++)
                #pragma unroll
                for (int j = 0; j < 4; j++) acc[i][j] += xv[i] * wv[j];
        }
        __syncthreads();
    }
    #pragma unroll
    for (int i = 0; i < 4; i++) {
        int r = row0 + ty * 4 + i;
        int s = r & (SS - 1);                 // sequence position
        float* yrow = Y + (size_t)r * PC + col0 + tx * 4;
        if (ROPE) {
            #pragma unroll
            for (int jp = 0; jp < 2; jp++) {
                int c = col0 + tx * 4 + jp * 2;
                int dl = c & 63;              // d within head
                int ii = dl >> 1;             // pair index 0..31
                float freq = expf(-((float)(2 * ii) / 64.0f) * logf(10000.0f));
                float ang = (float)s * freq;
                float sn, cs;
                sincosf(ang, &sn, &cs);
                float x1 = acc[i][jp * 2], x2 = acc[i][jp * 2 + 1];
                yrow[jp * 2]     = x1 * cs - x2 * sn;
                yrow[jp * 2 + 1] = x1 * sn + x2 * cs;
            }
        } else {
            #pragma unroll
            for (int j = 0; j < 4; j++) yrow[j] = acc[i][j];
        }
    }
}

// ---------- flash attention, 64-row Q tile, full (non-causal) ----------
__global__ __launch_bounds__(256) void attn_kernel(const float* __restrict__ Qs,
                                                   const float* __restrict__ K,
                                                   const float* __restrict__ V,
                                                   float* __restrict__ O) {
    __shared__ float Qt[64][65];    // TRANSPOSED: [d][row]
    __shared__ float KVt[64][65];   // K then V, phase-shared: [key][d]
    __shared__ float St[64][65];    // scores / probs
    __shared__ float mrow[64], lrow[64], arow[64];
    int qt = blockIdx.x, h = blockIdx.y, b = blockIdx.z;
    int tid = threadIdx.x;
    int tx = tid & 15, ty = tid >> 4;
    size_t base = (size_t)b * SS * PC + h * 64;   // row stride PC=256
    int q0 = qt * 64;
    // Q tile -> LDS transposed
    for (int i = 0; i < 16; i++) {
        int idx = i * 256 + tid;    // 0..4095
        int r = idx >> 6, d = idx & 63;
        Qt[d][r] = Qs[base + (size_t)(q0 + r) * PC + d];
    }
    if (tid < 64) { mrow[tid] = -INFINITY; lrow[tid] = 0.0f; }
    float o[4][4] = {};
    const float scale = 0.125f;     // 1/sqrt(64)
    for (int kt = 0; kt < 32; kt++) {
        int a0 = kt * 64;
        __syncthreads();            // prior V/St reads done (and Q load at kt=0)
        for (int i = 0; i < 16; i++) {
            int idx = i * 256 + tid;
            int r = idx >> 6, d = idx & 63;
            KVt[r][d] = K[base + (size_t)(a0 + r) * PC + d];
        }
        __syncthreads();
        // S = Q K^T (scaled)
        float sv[4][4] = {};
        #pragma unroll 8
        for (int kk = 0; kk < 64; kk++) {
            float qv[4], kvv[4];
            #pragma unroll
            for (int i = 0; i < 4; i++) qv[i] = Qt[kk][ty * 4 + i];
            #pragma unroll
            for (int j = 0; j < 4; j++) kvv[j] = KVt[tx * 4 + j][kk];
            #pragma unroll
            for (int i = 0; i < 4; i++)
                #pragma unroll
                for (int j = 0; j < 4; j++) sv[i][j] += qv[i] * kvv[j];
        }
        #pragma unroll
        for (int i = 0; i < 4; i++)
            #pragma unroll
            for (int j = 0; j < 4; j++) St[ty * 4 + i][tx * 4 + j] = sv[i][j] * scale;
        __syncthreads();            // St ready; all K reads done
        // load V (all threads) + online softmax (wave 0)
        for (int i = 0; i < 16; i++) {
            int idx = i * 256 + tid;
            int r = idx >> 6, d = idx & 63;
            KVt[r][d] = V[base + (size_t)(a0 + r) * PC + d];
        }
        if (tid < 64) {
            int r = tid;
            float m_old = mrow[r];
            float mx = m_old;
            #pragma unroll 8
            for (int c = 0; c < 64; c++) mx = fmaxf(mx, St[r][c]);
            float alpha = __expf(m_old - mx);   // exp(-inf)=0 on first tile
            float sum = 0.0f;
            #pragma unroll 8
            for (int c = 0; c < 64; c++) {
                float p = __expf(St[r][c] - mx);
                St[r][c] = p;
                sum += p;
            }
            lrow[r] = lrow[r] * alpha + sum;
            mrow[r] = mx;
            arow[r] = alpha;
        }
        __syncthreads();
        // O = O*alpha + P V
        #pragma unroll
        for (int i = 0; i < 4; i++) {
            float al = arow[ty * 4 + i];
            #pragma unroll
            for (int j = 0; j < 4; j++) o[i][j] *= al;
        }
        #pragma unroll 8
        for (int c = 0; c < 64; c++) {
            float pv[4], vv[4];
            #pragma unroll
            for (int i = 0; i < 4; i++) pv[i] = St[ty * 4 + i][c];
            #pragma unroll
            for (int j = 0; j < 4; j++) vv[j] = KVt[c][tx * 4 + j];
            #pragma unroll
            for (int i = 0; i < 4; i++)
                #pragma unroll
                for (int j = 0; j < 4; j++) o[i][j] += pv[i] * vv[j];
        }
    }
    // write O / l   (lrow last written before final barrier -> safe)
    #pragma unroll
    for (int i = 0; i < 4; i++) {
        int r = ty * 4 + i;
        float inv_l = 1.0f / lrow[r];
        #pragma unroll
        for (int j = 0; j < 4; j++)
            O[base + (size_t)(q0 + r) * PC + tx * 4 + j] = o[i][j] * inv_l;
    }
}

// ---------- mean over heads + @ Wo : out[NROW][1024] ----------
__global__ __launch_bounds__(256) void outproj_kernel(const float* __restrict__ O,
                                                      const float* __restrict__ Wo,
                                                      float* __restrict__ out) {
    __shared__ float Om[64][65];   // [m][k=64]
    __shared__ float Wt[64][65];   // [k][n]
    int bm = blockIdx.x;           // 128
    int bn = blockIdx.y;           // 16
    int tid = threadIdx.x;
    int tx = tid & 15, ty = tid >> 4;
    int row0 = bm * 64, col0 = bn * 64;
    for (int i = 0; i < 16; i++) {
        int idx = i * 256 + tid;
        int r = idx >> 6, d = idx & 63;
        const float* p = O + (size_t)(row0 + r) * PC + d;
        Om[r][d] = 0.25f * (p[0] + p[64] + p[128] + p[192]);
    }
    for (int i = 0; i < 16; i++) {
        int idx = i * 256 + tid;
        int r = idx >> 6, c = idx & 63;
        Wt[r][c] = Wo[(size_t)r * EE + col0 + c];
    }
    __syncthreads();
    float acc[4][4] = {};
    #pragma unroll 8
    for (int kk = 0; kk < 64; kk++) {
        float ov[4], wv[4];
        #pragma unroll
        for (int i = 0; i < 4; i++) ov[i] = Om[ty * 4 + i][kk];
        #pragma unroll
        for (int j = 0; j < 4; j++) wv[j] = Wt[kk][tx * 4 + j];
        #pragma unroll
        for (int i = 0; i < 4; i++)
            #pragma unroll
            for (int j = 0; j < 4; j++) acc[i][j] += ov[i] * wv[j];
    }
    #pragma unroll
    for (int i = 0; i < 4; i++)
        #pragma unroll
        for (int j = 0; j < 4; j++)
            out[(size_t)(row0 + ty * 4 + i) * EE + col0 + tx * 4 + j] = acc[i][j];
}

extern "C" void kernel_launch(void* const* d_in, const int* in_sizes, int n_in,
                              void* d_out, int out_size, void* d_ws, size_t ws_size,
                              hipStream_t stream) {
    const float* q  = (const float*)d_in[0];
    const float* kv = (const float*)d_in[1];
    const float* Wq = (const float*)d_in[2];
    const float* Wk = (const float*)d_in[3];
    const float* Wv = (const float*)d_in[4];
    const float* Wo = (const float*)d_in[5];
    float* out = (float*)d_out;
    float* ws  = (float*)d_ws;

    float* Wqs = ws;                    // 262144 floats
    float* Qs  = Wqs + 262144;          // 2097152 floats  [row][h*64+d]
    float* Kp  = Qs + 2097152;          // 2097152
    float* Vp  = Kp + 2097152;          // 2097152
    float* O   = Vp + 2097152;          // 2097152
    // total ws use: 8650752 floats = 34.6 MB

    wq_reduce_kernel<<<1024, 256, 0, stream>>>(Wq, Wqs);

    dim3 pg(128, 4);
    proj_kernel<true ><<<pg, 256, 0, stream>>>(q,  Wqs, Qs);   // group-summed Q + rope
    proj_kernel<true ><<<pg, 256, 0, stream>>>(kv, Wk,  Kp);   // K + rope
    proj_kernel<false><<<pg, 256, 0, stream>>>(kv, Wv,  Vp);   // V

    dim3 ag(32, NH, BB);
    attn_kernel<<<ag, 256, 0, stream>>>(Qs, Kp, Vp, O);

    dim3 og(128, 16);
    outproj_kernel<<<og, 256, 0, stream>>>(O, Wo, out);
}

// Round 3
// 334.857 us; speedup vs baseline: 2.6890x; 2.6890x over previous
//
#include <hip/hip_runtime.h>
#include <math.h>

#define SS 2048
#define EE 1024

using bf16x8 = __attribute__((ext_vector_type(8))) short;
using f32x4  = __attribute__((ext_vector_type(4))) float;

__device__ inline short f2bf(float x) {
    unsigned u = __builtin_bit_cast(unsigned, x);
    return (short)((u + 0x7fffu + ((u >> 16) & 1u)) >> 16);
}

// ---------- weight prep: transpose to [N][K] bf16, group-sum Wq, fold 0.25 into Wo ----------
__global__ __launch_bounds__(256) void prep_weights(const float* __restrict__ Wq,
                                                    const float* __restrict__ Wk,
                                                    const float* __restrict__ Wv,
                                                    const float* __restrict__ Wo,
                                                    short* __restrict__ WqT,
                                                    short* __restrict__ WkvT,
                                                    short* __restrict__ Wo4) {
    int idx = blockIdx.x * 256 + threadIdx.x;   // 262144 = 256 c * 1024 e
    int c = idx >> 10, e = idx & 1023;
    int h = c >> 6, d = c & 63;
    const float* p = Wq + (size_t)e * 1024 + h * 256 + d;   // Wq[e][h*4+g][d]
    WqT[(size_t)c * 1024 + e] = f2bf(p[0] + p[64] + p[128] + p[192]);
    WkvT[(size_t)c * 1024 + e]         = f2bf(Wk[(size_t)e * 256 + c]);
    WkvT[(size_t)(256 + c) * 1024 + e] = f2bf(Wv[(size_t)e * 256 + c]);
    // out-proj consumes B^T = [N=e][K=c]  (round-2 bug: was written [c][e])
    Wo4[(size_t)e * 256 + c] = f2bf(0.25f * Wo[(size_t)d * 1024 + e]);
}

// ---------- generic bf16 MFMA GEMM: C[M][*] = A[M][K] * B^T[N][K] ----------
// BM=128, BK=64, 4 waves in 2x2, wave tile 64 x (BN/2).
// ROPELIM>0: cols<ROPELIM get rope (s=row&2047, d=col&63), output bf16 stride 256,
//            cols>=256 go to Y1 at col-256 (the V half of the fused KV proj).
// OUTBF16=false: plain fp32 store to Y0 stride 1024.
template<int BN, int KTOT, bool ABF16, bool OUTBF16, int ROPELIM>
__global__ __launch_bounds__(256) void gemm_kernel(const void* __restrict__ Ap,
                                                   const short* __restrict__ Bp,
                                                   void* __restrict__ Y0,
                                                   short* __restrict__ Y1) {
    constexpr int NT = BN / 32;
    __shared__ short As[128][72];
    __shared__ short Bs[BN][72];
    int tid = threadIdx.x;
    int wave = tid >> 6, lane = tid & 63, quad = lane >> 4, c16 = lane & 15;
    int wm = wave >> 1, wn = wave & 1;
    int m0 = blockIdx.x * 128, n0 = blockIdx.y * BN;

    f32x4 acc[4][NT];
    #pragma unroll
    for (int i = 0; i < 4; i++)
        #pragma unroll
        for (int j = 0; j < NT; j++) acc[i][j] = (f32x4){0.f, 0.f, 0.f, 0.f};

    for (int k0 = 0; k0 < KTOT; k0 += 64) {
        if (ABF16) {
            const short* A = (const short*)Ap;
            #pragma unroll
            for (int i = 0; i < 4; i++) {
                int id = i * 256 + tid, r = id >> 3, ch = id & 7;
                *(int4*)&As[r][ch * 8] =
                    *(const int4*)&A[(size_t)(m0 + r) * KTOT + k0 + ch * 8];
            }
        } else {
            const float* A = (const float*)Ap;
            #pragma unroll
            for (int i = 0; i < 8; i++) {
                int id = i * 256 + tid, r = id >> 4, ch = id & 15;
                float4 v = *(const float4*)&A[(size_t)(m0 + r) * KTOT + k0 + ch * 4];
                short4 s4;
                s4.x = f2bf(v.x); s4.y = f2bf(v.y); s4.z = f2bf(v.z); s4.w = f2bf(v.w);
                *(short4*)&As[r][ch * 4] = s4;
            }
        }
        #pragma unroll
        for (int i = 0; i < BN / 32; i++) {
            int id = i * 256 + tid, r = id >> 3, ch = id & 7;
            *(int4*)&Bs[r][ch * 8] =
                *(const int4*)&Bp[(size_t)(n0 + r) * KTOT + k0 + ch * 8];
        }
        __syncthreads();
        #pragma unroll
        for (int ks = 0; ks < 64; ks += 32) {
            bf16x8 af[4], bfr[NT];
            #pragma unroll
            for (int mt = 0; mt < 4; mt++)
                af[mt] = *(const bf16x8*)&As[wm * 64 + mt * 16 + c16][ks + quad * 8];
            #pragma unroll
            for (int nt = 0; nt < NT; nt++)
                bfr[nt] = *(const bf16x8*)&Bs[wn * (BN / 2) + nt * 16 + c16][ks + quad * 8];
            #pragma unroll
            for (int mt = 0; mt < 4; mt++)
                #pragma unroll
                for (int nt = 0; nt < NT; nt++)
                    acc[mt][nt] = __builtin_amdgcn_mfma_f32_16x16x32_bf16(
                        af[mt], bfr[nt], acc[mt][nt], 0, 0, 0);
        }
        __syncthreads();
    }
    // epilogue
    #pragma unroll
    for (int mt = 0; mt < 4; mt++) {
        #pragma unroll
        for (int nt = 0; nt < NT; nt++) {
            int col = n0 + wn * (BN / 2) + nt * 16 + c16;
            int rowb = m0 + wm * 64 + mt * 16 + quad * 4;
            f32x4 v = acc[mt][nt];
            if (ROPELIM > 0 && col < ROPELIM) {
                int d = col & 63, ii = d >> 1;
                float freq = __expf(-(float)ii * (9.210340371976184f / 32.0f));
                float sgn = (lane & 1) ? 1.0f : -1.0f;
                #pragma unroll
                for (int r = 0; r < 4; r++) {
                    int row = rowb + r;
                    float ang = (float)(row & (SS - 1)) * freq;
                    float sn, cs;
                    sincosf(ang, &sn, &cs);
                    float other = __shfl_xor(v[r], 1);
                    float res = v[r] * cs + sgn * sn * other;
                    short* t = (col < 256) ? ((short*)Y0 + (size_t)row * 256 + col)
                                           : (Y1 + (size_t)row * 256 + col - 256);
                    *t = f2bf(res);
                }
            } else {
                #pragma unroll
                for (int r = 0; r < 4; r++) {
                    int row = rowb + r;
                    if (OUTBF16) {
                        short* t = (col < 256) ? ((short*)Y0 + (size_t)row * 256 + col)
                                               : (Y1 + (size_t)row * 256 + col - 256);
                        *t = f2bf(v[r]);
                    } else {
                        ((float*)Y0)[(size_t)row * 1024 + col] = v[r];
                    }
                }
            }
        }
    }
}

// ---------- V transpose: Vb[b*2048+s][h*64+d] -> Vt[(b*4+h)*64+d][s] ----------
__global__ __launch_bounds__(256) void transpose_v(const short* __restrict__ Vb,
                                                   short* __restrict__ Vt) {
    __shared__ short T[64][72];
    int t = threadIdx.x;
    int s0 = blockIdx.x * 64, h = blockIdx.y, b = blockIdx.z;
    #pragma unroll
    for (int i = 0; i < 2; i++) {
        int id = i * 256 + t, sl = id >> 3, ch = id & 7;
        *(int4*)&T[sl][ch * 8] =
            *(const int4*)&Vb[((size_t)(b * SS + s0 + sl)) * 256 + h * 64 + ch * 8];
    }
    __syncthreads();
    #pragma unroll
    for (int i = 0; i < 2; i++) {
        int id = i * 256 + t, d = id >> 3, ch = id & 7;
        bf16x8 o;
        #pragma unroll
        for (int j = 0; j < 8; j++) o[j] = T[ch * 8 + j][d];
        *(bf16x8*)&Vt[((size_t)((b * 4 + h) * 64 + d)) * SS + s0 + ch * 8] = o;
    }
}

// ---------- MFMA flash attention: 64 Q-rows/block, 4 waves x 16-row strips ----------
__global__ __launch_bounds__(256) void attn_kernel(const short* __restrict__ Qb,
                                                   const short* __restrict__ Kb,
                                                   const short* __restrict__ Vt,
                                                   float* __restrict__ Ob) {
    __shared__ short Qs[64][72], Ks[64][72], Vs[64][72];
    __shared__ short Ps[4][16][72];
    int tid = threadIdx.x;
    int wave = tid >> 6, lane = tid & 63, quad = lane >> 4, c16 = lane & 15;
    int qt = blockIdx.x, h = blockIdx.y, b = blockIdx.z;
    int q0 = qt * 64;
    size_t qkbase = (size_t)b * SS * 256 + h * 64;
    size_t vtbase = (size_t)((b * 4 + h) * 64) * SS;

    #pragma unroll
    for (int i = 0; i < 2; i++) {
        int id = i * 256 + tid, r = id >> 3, ch = id & 7;
        *(int4*)&Qs[r][ch * 8] = *(const int4*)&Qb[qkbase + (size_t)(q0 + r) * 256 + ch * 8];
    }
    float m[4], l[4];
    f32x4 o[4];
    #pragma unroll
    for (int r = 0; r < 4; r++) { m[r] = -INFINITY; l[r] = 0.0f; }
    #pragma unroll
    for (int dt = 0; dt < 4; dt++) o[dt] = (f32x4){0.f, 0.f, 0.f, 0.f};

    for (int kt = 0; kt < 32; kt++) {
        int a0 = kt * 64;
        __syncthreads();
        #pragma unroll
        for (int i = 0; i < 2; i++) {
            int id = i * 256 + tid, r = id >> 3, ch = id & 7;
            *(int4*)&Ks[r][ch * 8] =
                *(const int4*)&Kb[qkbase + (size_t)(a0 + r) * 256 + ch * 8];
            *(int4*)&Vs[r][ch * 8] =
                *(const int4*)&Vt[vtbase + (size_t)r * SS + a0 + ch * 8];
        }
        __syncthreads();
        // S = Q K^T for this wave's 16-row strip
        f32x4 sv[4];
        #pragma unroll
        for (int nt = 0; nt < 4; nt++) sv[nt] = (f32x4){0.f, 0.f, 0.f, 0.f};
        #pragma unroll
        for (int ks = 0; ks < 64; ks += 32) {
            bf16x8 aq = *(const bf16x8*)&Qs[wave * 16 + c16][ks + quad * 8];
            #pragma unroll
            for (int nt = 0; nt < 4; nt++) {
                bf16x8 bk = *(const bf16x8*)&Ks[nt * 16 + c16][ks + quad * 8];
                sv[nt] = __builtin_amdgcn_mfma_f32_16x16x32_bf16(aq, bk, sv[nt], 0, 0, 0);
            }
        }
        #pragma unroll
        for (int nt = 0; nt < 4; nt++)
            #pragma unroll
            for (int r = 0; r < 4; r++) sv[nt][r] *= 0.125f;
        // online softmax: row r lives in 16 lanes (same quad), 4 tiles
        float mx[4], al[4], sum[4];
        #pragma unroll
        for (int r = 0; r < 4; r++)
            mx[r] = fmaxf(fmaxf(sv[0][r], sv[1][r]), fmaxf(sv[2][r], sv[3][r]));
        #pragma unroll
        for (int off = 1; off < 16; off <<= 1)
            #pragma unroll
            for (int r = 0; r < 4; r++) mx[r] = fmaxf(mx[r], __shfl_xor(mx[r], off));
        #pragma unroll
        for (int r = 0; r < 4; r++) {
            float nm = fmaxf(m[r], mx[r]);
            al[r] = __expf(m[r] - nm);
            m[r] = nm;
        }
        #pragma unroll
        for (int nt = 0; nt < 4; nt++)
            #pragma unroll
            for (int r = 0; r < 4; r++) sv[nt][r] = __expf(sv[nt][r] - m[r]);
        #pragma unroll
        for (int r = 0; r < 4; r++)
            sum[r] = (sv[0][r] + sv[1][r]) + (sv[2][r] + sv[3][r]);
        #pragma unroll
        for (int off = 1; off < 16; off <<= 1)
            #pragma unroll
            for (int r = 0; r < 4; r++) sum[r] += __shfl_xor(sum[r], off);
        #pragma unroll
        for (int r = 0; r < 4; r++) l[r] = l[r] * al[r] + sum[r];
        // P -> LDS (C-layout positions), re-read as A-layout fragments (same wave)
        #pragma unroll
        for (int nt = 0; nt < 4; nt++)
            #pragma unroll
            for (int r = 0; r < 4; r++)
                Ps[wave][quad * 4 + r][nt * 16 + c16] = f2bf(sv[nt][r]);
        #pragma unroll
        for (int dt = 0; dt < 4; dt++)
            #pragma unroll
            for (int r = 0; r < 4; r++) o[dt][r] *= al[r];
        #pragma unroll
        for (int ks = 0; ks < 64; ks += 32) {
            bf16x8 ap = *(const bf16x8*)&Ps[wave][c16][ks + quad * 8];
            #pragma unroll
            for (int dt = 0; dt < 4; dt++) {
                bf16x8 bv = *(const bf16x8*)&Vs[dt * 16 + c16][ks + quad * 8];
                o[dt] = __builtin_amdgcn_mfma_f32_16x16x32_bf16(ap, bv, o[dt], 0, 0, 0);
            }
        }
    }
    #pragma unroll
    for (int r = 0; r < 4; r++) l[r] = 1.0f / l[r];
    #pragma unroll
    for (int dt = 0; dt < 4; dt++)
        #pragma unroll
        for (int r = 0; r < 4; r++) {
            int row = q0 + wave * 16 + quad * 4 + r;
            Ob[qkbase + (size_t)row * 256 + dt * 16 + c16] = o[dt][r] * l[r];
        }
}

extern "C" void kernel_launch(void* const* d_in, const int* in_sizes, int n_in,
                              void* d_out, int out_size, void* d_ws, size_t ws_size,
                              hipStream_t stream) {
    const float* q  = (const float*)d_in[0];
    const float* kv = (const float*)d_in[1];
    const float* Wq = (const float*)d_in[2];
    const float* Wk = (const float*)d_in[3];
    const float* Wv = (const float*)d_in[4];
    const float* Wo = (const float*)d_in[5];
    float* out = (float*)d_out;

    short* Qb   = (short*)d_ws;        // 2097152 bf16
    short* Kb   = Qb + 2097152;
    short* Vb   = Kb + 2097152;
    short* Vt   = Vb + 2097152;
    short* WqT  = Vt + 2097152;        // 262144
    short* WkvT = WqT + 262144;        // 524288
    short* Wo4  = WkvT + 524288;       // 262144
    float* Ob   = (float*)(Wo4 + 262144);  // 2097152 fp32 (byte offset 18874368, 16B-aligned)
    // total ws use: ~27.3 MB

    prep_weights<<<1024, 256, 0, stream>>>(Wq, Wk, Wv, Wo, WqT, WkvT, Wo4);

    // Q projection (group-summed weights), rope all 256 cols
    gemm_kernel<64, 1024, false, true, 256>
        <<<dim3(64, 4), 256, 0, stream>>>(q, WqT, Qb, Qb);
    // fused K+V projection: N=512, rope on K half (cols<256), V half -> Vb
    gemm_kernel<128, 1024, false, true, 256>
        <<<dim3(64, 4), 256, 0, stream>>>(kv, WkvT, Kb, Vb);

    transpose_v<<<dim3(32, 4, 4), 256, 0, stream>>>(Vb, Vt);

    attn_kernel<<<dim3(32, 4, 4), 256, 0, stream>>>(Qb, Kb, Vt, Ob);

    // output projection: mean-over-heads folded into Wo4, K=256, fp32 A, fp32 out
    gemm_kernel<128, 256, false, false, 0>
        <<<dim3(64, 8), 256, 0, stream>>>(Ob, Wo4, out, nullptr);
}

// Round 4
// 212.440 us; speedup vs baseline: 4.2386x; 1.5762x over previous
//
#include <hip/hip_runtime.h>
#include <math.h>

#define SS 2048
#define EE 1024

using bf16x8 = __attribute__((ext_vector_type(8))) short;
using f32x4  = __attribute__((ext_vector_type(4))) float;

__device__ inline short f2bf(float x) {
    unsigned u = __builtin_bit_cast(unsigned, x);
    return (short)((u + 0x7fffu + ((u >> 16) & 1u)) >> 16);
}

// ---------- weight prep ----------
// Wall[768][1024] bf16 B^T: rows 0-255 = group-summed Wq * 0.125*log2e (score scale
// + exp2 base change folded in), 256-511 = Wk, 512-767 = Wv.
// Wo4[1024][256] = 0.25 * Wo^T (mean over heads folded).
__global__ __launch_bounds__(256) void prep_weights(const float* __restrict__ Wq,
                                                    const float* __restrict__ Wk,
                                                    const float* __restrict__ Wv,
                                                    const float* __restrict__ Wo,
                                                    short* __restrict__ Wall,
                                                    short* __restrict__ Wo4) {
    int idx = blockIdx.x * 256 + threadIdx.x;   // 262144 = 256 c * 1024 e
    int c = idx >> 10, e = idx & 1023;
    int h = c >> 6, d = c & 63;
    const float* p = Wq + (size_t)e * 1024 + h * 256 + d;   // Wq[e][h*4+g][d]
    Wall[(size_t)c * 1024 + e] = f2bf(0.18033688011112042f * (p[0] + p[64] + p[128] + p[192]));
    Wall[(size_t)(256 + c) * 1024 + e] = f2bf(Wk[(size_t)e * 256 + c]);
    Wall[(size_t)(512 + c) * 1024 + e] = f2bf(Wv[(size_t)e * 256 + c]);
    Wo4[(size_t)e * 256 + c] = f2bf(0.25f * Wo[(size_t)d * 1024 + e]);
}

// ---------- fused Q/K/V projection: one launch, 768 blocks ----------
// C[8192][768] = A[8192][1024] @ Wall^T, rope on cols<512, scatter to Qb/Kb/Vb.
__global__ __launch_bounds__(256) void proj_kernel(const float* __restrict__ q,
                                                   const float* __restrict__ kv,
                                                   const short* __restrict__ Wall,
                                                   short* __restrict__ Qb,
                                                   short* __restrict__ Kb,
                                                   short* __restrict__ Vb) {
    __shared__ short As[128][72];
    __shared__ short Bs[64][72];
    int tid = threadIdx.x;
    int wave = tid >> 6, lane = tid & 63, quad = lane >> 4, c16 = lane & 15;
    int wm = wave >> 1, wn = wave & 1;
    int m0 = blockIdx.x * 128, n0 = blockIdx.y * 64;
    const float* A = (n0 < 256) ? q : kv;

    f32x4 acc[4][2];
    #pragma unroll
    for (int i = 0; i < 4; i++)
        #pragma unroll
        for (int j = 0; j < 2; j++) acc[i][j] = (f32x4){0.f, 0.f, 0.f, 0.f};

    for (int k0 = 0; k0 < 1024; k0 += 64) {
        #pragma unroll
        for (int i = 0; i < 8; i++) {
            int id = i * 256 + tid, r = id >> 4, ch = id & 15;
            float4 v = *(const float4*)&A[(size_t)(m0 + r) * 1024 + k0 + ch * 4];
            short4 s4;
            s4.x = f2bf(v.x); s4.y = f2bf(v.y); s4.z = f2bf(v.z); s4.w = f2bf(v.w);
            *(short4*)&As[r][ch * 4] = s4;
        }
        #pragma unroll
        for (int i = 0; i < 2; i++) {
            int id = i * 256 + tid, r = id >> 3, ch = id & 7;
            *(int4*)&Bs[r][ch * 8] =
                *(const int4*)&Wall[(size_t)(n0 + r) * 1024 + k0 + ch * 8];
        }
        __syncthreads();
        #pragma unroll
        for (int ks = 0; ks < 64; ks += 32) {
            bf16x8 af[4], bfr[2];
            #pragma unroll
            for (int mt = 0; mt < 4; mt++)
                af[mt] = *(const bf16x8*)&As[wm * 64 + mt * 16 + c16][ks + quad * 8];
            #pragma unroll
            for (int nt = 0; nt < 2; nt++)
                bfr[nt] = *(const bf16x8*)&Bs[wn * 32 + nt * 16 + c16][ks + quad * 8];
            #pragma unroll
            for (int mt = 0; mt < 4; mt++)
                #pragma unroll
                for (int nt = 0; nt < 2; nt++)
                    acc[mt][nt] = __builtin_amdgcn_mfma_f32_16x16x32_bf16(
                        af[mt], bfr[nt], acc[mt][nt], 0, 0, 0);
        }
        __syncthreads();
    }
    #pragma unroll
    for (int mt = 0; mt < 4; mt++) {
        #pragma unroll
        for (int nt = 0; nt < 2; nt++) {
            int col = n0 + wn * 32 + nt * 16 + c16;
            int rowb = m0 + wm * 64 + mt * 16 + quad * 4;
            f32x4 v = acc[mt][nt];
            short* dst = (col < 256) ? (Qb + col)
                       : (col < 512) ? (Kb + col - 256)
                                     : (Vb + col - 512);
            if (col < 512) {
                int d = col & 63, ii = d >> 1;
                float freq = __expf(-(float)ii * (9.210340371976184f / 32.0f));
                float sgn = (lane & 1) ? 1.0f : -1.0f;
                #pragma unroll
                for (int r = 0; r < 4; r++) {
                    int row = rowb + r;
                    float ang = (float)(row & (SS - 1)) * freq;
                    float sn, cs;
                    sincosf(ang, &sn, &cs);
                    float other = __shfl_xor(v[r], 1);
                    dst[(size_t)row * 256] = f2bf(v[r] * cs + sgn * sn * other);
                }
            } else {
                #pragma unroll
                for (int r = 0; r < 4; r++)
                    dst[(size_t)(rowb + r) * 256] = f2bf(v[r]);
            }
        }
    }
}

// ---------- V transpose: Vb[b*2048+s][h*64+d] -> Vt[(b*4+h)*64+d][s] ----------
__global__ __launch_bounds__(256) void transpose_v(const short* __restrict__ Vb,
                                                   short* __restrict__ Vt) {
    __shared__ short T[64][72];
    int t = threadIdx.x;
    int s0 = blockIdx.x * 64, h = blockIdx.y, b = blockIdx.z;
    #pragma unroll
    for (int i = 0; i < 2; i++) {
        int id = i * 256 + t, sl = id >> 3, ch = id & 7;
        *(int4*)&T[sl][ch * 8] =
            *(const int4*)&Vb[((size_t)(b * SS + s0 + sl)) * 256 + h * 64 + ch * 8];
    }
    __syncthreads();
    #pragma unroll
    for (int i = 0; i < 2; i++) {
        int id = i * 256 + t, d = id >> 3, ch = id & 7;
        bf16x8 o;
        #pragma unroll
        for (int j = 0; j < 8; j++) o[j] = T[ch * 8 + j][d];
        *(bf16x8*)&Vt[((size_t)((b * 4 + h) * 64 + d)) * SS + s0 + ch * 8] = o;
    }
}

// ---------- MFMA flash attention, static max, K-split x2 ----------
// grid (32 qt, 16 bh, 2 kc). Q pre-scaled so P = exp2(S). Partials out.
__global__ __launch_bounds__(256) void attn_kernel(const short* __restrict__ Qb,
                                                   const short* __restrict__ Kb,
                                                   const short* __restrict__ Vt,
                                                   float* __restrict__ Opart,
                                                   float* __restrict__ Lpart) {
    __shared__ short Qs[64][72], Ks[64][72], Vs[64][72];
    __shared__ short Ps[4][16][72];
    int tid = threadIdx.x;
    int wave = tid >> 6, lane = tid & 63, quad = lane >> 4, c16 = lane & 15;
    int qt = blockIdx.x, bh = blockIdx.y, kc = blockIdx.z;
    int q0 = qt * 64;
    size_t qkbase = (size_t)(bh >> 2) * SS * 256 + (bh & 3) * 64;
    size_t vtbase = (size_t)(bh * 64) * SS;
    size_t pbase  = (size_t)(kc * 16 + bh) * SS;

    #pragma unroll
    for (int i = 0; i < 2; i++) {
        int id = i * 256 + tid, r = id >> 3, ch = id & 7;
        *(int4*)&Qs[r][ch * 8] = *(const int4*)&Qb[qkbase + (size_t)(q0 + r) * 256 + ch * 8];
    }
    __syncthreads();
    // Q A-fragments are loop-invariant: hoist
    bf16x8 aq0 = *(const bf16x8*)&Qs[wave * 16 + c16][quad * 8];
    bf16x8 aq1 = *(const bf16x8*)&Qs[wave * 16 + c16][32 + quad * 8];

    float lsum[4] = {0.f, 0.f, 0.f, 0.f};
    f32x4 o[4];
    #pragma unroll
    for (int dt = 0; dt < 4; dt++) o[dt] = (f32x4){0.f, 0.f, 0.f, 0.f};

    for (int kt = 0; kt < 16; kt++) {
        int a0 = kc * 1024 + kt * 64;
        __syncthreads();
        #pragma unroll
        for (int i = 0; i < 2; i++) {
            int id = i * 256 + tid, r = id >> 3, ch = id & 7;
            *(int4*)&Ks[r][ch * 8] =
                *(const int4*)&Kb[qkbase + (size_t)(a0 + r) * 256 + ch * 8];
            *(int4*)&Vs[r][ch * 8] =
                *(const int4*)&Vt[vtbase + (size_t)r * SS + a0 + ch * 8];
        }
        __syncthreads();
        // S = Q K^T (already in log2 domain)
        f32x4 sv[4];
        #pragma unroll
        for (int nt = 0; nt < 4; nt++) sv[nt] = (f32x4){0.f, 0.f, 0.f, 0.f};
        #pragma unroll
        for (int nt = 0; nt < 4; nt++) {
            bf16x8 bk0 = *(const bf16x8*)&Ks[nt * 16 + c16][quad * 8];
            bf16x8 bk1 = *(const bf16x8*)&Ks[nt * 16 + c16][32 + quad * 8];
            sv[nt] = __builtin_amdgcn_mfma_f32_16x16x32_bf16(aq0, bk0, sv[nt], 0, 0, 0);
            sv[nt] = __builtin_amdgcn_mfma_f32_16x16x32_bf16(aq1, bk1, sv[nt], 0, 0, 0);
        }
        // P = 2^S  (no max tracking: |S| stays far below fp32 overflow)
        #pragma unroll
        for (int nt = 0; nt < 4; nt++)
            #pragma unroll
            for (int r = 0; r < 4; r++) sv[nt][r] = __builtin_exp2f(sv[nt][r]);
        #pragma unroll
        for (int r = 0; r < 4; r++)
            lsum[r] += (sv[0][r] + sv[1][r]) + (sv[2][r] + sv[3][r]);
        // P -> LDS (C-layout positions), re-read as A-fragments (same wave)
        #pragma unroll
        for (int nt = 0; nt < 4; nt++)
            #pragma unroll
            for (int r = 0; r < 4; r++)
                Ps[wave][quad * 4 + r][nt * 16 + c16] = f2bf(sv[nt][r]);
        #pragma unroll
        for (int ks = 0; ks < 64; ks += 32) {
            bf16x8 ap = *(const bf16x8*)&Ps[wave][c16][ks + quad * 8];
            #pragma unroll
            for (int dt = 0; dt < 4; dt++) {
                bf16x8 bv = *(const bf16x8*)&Vs[dt * 16 + c16][ks + quad * 8];
                o[dt] = __builtin_amdgcn_mfma_f32_16x16x32_bf16(ap, bv, o[dt], 0, 0, 0);
            }
        }
    }
    // one butterfly reduce of l over the 16 lanes of each quad
    #pragma unroll
    for (int off = 1; off < 16; off <<= 1)
        #pragma unroll
        for (int r = 0; r < 4; r++) lsum[r] += __shfl_xor(lsum[r], off);
    #pragma unroll
    for (int dt = 0; dt < 4; dt++)
        #pragma unroll
        for (int r = 0; r < 4; r++) {
            int row = q0 + wave * 16 + quad * 4 + r;
            Opart[(pbase + row) * 64 + dt * 16 + c16] = o[dt][r];
        }
    if (c16 == 0)
        #pragma unroll
        for (int r = 0; r < 4; r++)
            Lpart[pbase + q0 + wave * 16 + quad * 4 + r] = lsum[r];
}

// ---------- combine K-split partials: Ob = (sum O) / (sum l) ----------
__global__ __launch_bounds__(256) void combine_kernel(const float* __restrict__ Opart,
                                                      const float* __restrict__ Lpart,
                                                      float* __restrict__ Ob) {
    int idx = blockIdx.x * 256 + threadIdx.x;   // 2,097,152 = 4b*2048s*4h*64d
    int d = idx & 63, h = (idx >> 6) & 3, s = (idx >> 8) & 2047, b = idx >> 19;
    int bh = b * 4 + h;
    size_t p0 = ((size_t)bh * SS + s) * 64 + d;
    size_t p1 = ((size_t)(16 + bh) * SS + s) * 64 + d;
    float o = Opart[p0] + Opart[p1];
    float l = Lpart[(size_t)bh * SS + s] + Lpart[(size_t)(16 + bh) * SS + s];
    Ob[((size_t)(b * SS + s)) * 256 + h * 64 + d] = o / l;
}

// ---------- output projection: out[8192][1024] = Ob[8192][256] @ Wo4^T ----------
__global__ __launch_bounds__(256) void outproj_kernel(const float* __restrict__ Ob,
                                                      const short* __restrict__ Wo4,
                                                      float* __restrict__ out) {
    __shared__ short As[128][72];
    __shared__ short Bs[128][72];
    int tid = threadIdx.x;
    int wave = tid >> 6, lane = tid & 63, quad = lane >> 4, c16 = lane & 15;
    int wm = wave >> 1, wn = wave & 1;
    int m0 = blockIdx.x * 128, n0 = blockIdx.y * 128;

    f32x4 acc[4][4];
    #pragma unroll
    for (int i = 0; i < 4; i++)
        #pragma unroll
        for (int j = 0; j < 4; j++) acc[i][j] = (f32x4){0.f, 0.f, 0.f, 0.f};

    for (int k0 = 0; k0 < 256; k0 += 64) {
        #pragma unroll
        for (int i = 0; i < 8; i++) {
            int id = i * 256 + tid, r = id >> 4, ch = id & 15;
            float4 v = *(const float4*)&Ob[(size_t)(m0 + r) * 256 + k0 + ch * 4];
            short4 s4;
            s4.x = f2bf(v.x); s4.y = f2bf(v.y); s4.z = f2bf(v.z); s4.w = f2bf(v.w);
            *(short4*)&As[r][ch * 4] = s4;
        }
        #pragma unroll
        for (int i = 0; i < 4; i++) {
            int id = i * 256 + tid, r = id >> 3, ch = id & 7;
            *(int4*)&Bs[r][ch * 8] =
                *(const int4*)&Wo4[(size_t)(n0 + r) * 256 + k0 + ch * 8];
        }
        __syncthreads();
        #pragma unroll
        for (int ks = 0; ks < 64; ks += 32) {
            bf16x8 af[4], bfr[4];
            #pragma unroll
            for (int mt = 0; mt < 4; mt++)
                af[mt] = *(const bf16x8*)&As[wm * 64 + mt * 16 + c16][ks + quad * 8];
            #pragma unroll
            for (int nt = 0; nt < 4; nt++)
                bfr[nt] = *(const bf16x8*)&Bs[wn * 64 + nt * 16 + c16][ks + quad * 8];
            #pragma unroll
            for (int mt = 0; mt < 4; mt++)
                #pragma unroll
                for (int nt = 0; nt < 4; nt++)
                    acc[mt][nt] = __builtin_amdgcn_mfma_f32_16x16x32_bf16(
                        af[mt], bfr[nt], acc[mt][nt], 0, 0, 0);
        }
        __syncthreads();
    }
    #pragma unroll
    for (int mt = 0; mt < 4; mt++)
        #pragma unroll
        for (int nt = 0; nt < 4; nt++) {
            int col = n0 + wn * 64 + nt * 16 + c16;
            int rowb = m0 + wm * 64 + mt * 16 + quad * 4;
            #pragma unroll
            for (int r = 0; r < 4; r++)
                out[(size_t)(rowb + r) * 1024 + col] = acc[mt][nt][r];
        }
}

extern "C" void kernel_launch(void* const* d_in, const int* in_sizes, int n_in,
                              void* d_out, int out_size, void* d_ws, size_t ws_size,
                              hipStream_t stream) {
    const float* q  = (const float*)d_in[0];
    const float* kv = (const float*)d_in[1];
    const float* Wq = (const float*)d_in[2];
    const float* Wk = (const float*)d_in[3];
    const float* Wv = (const float*)d_in[4];
    const float* Wo = (const float*)d_in[5];
    float* out = (float*)d_out;

    short* Qb    = (short*)d_ws;         // 2097152 bf16
    short* Kb    = Qb + 2097152;
    short* Vb    = Kb + 2097152;
    short* Vt    = Vb + 2097152;
    short* Wall  = Vt + 2097152;         // 786432 (WqT|WkT|WvT)
    short* Wo4   = Wall + 786432;        // 262144
    float* Ob    = (float*)(Wo4 + 262144);   // 2097152 fp32
    float* Opart = Ob + 2097152;         // 2*16*2048*64 = 4194304 fp32
    float* Lpart = Opart + 4194304;      // 65536 fp32
    // total ws use: ~43.5 MB

    prep_weights<<<1024, 256, 0, stream>>>(Wq, Wk, Wv, Wo, Wall, Wo4);

    proj_kernel<<<dim3(64, 12), 256, 0, stream>>>(q, kv, Wall, Qb, Kb, Vb);

    transpose_v<<<dim3(32, 4, 4), 256, 0, stream>>>(Vb, Vt);

    attn_kernel<<<dim3(32, 16, 2), 256, 0, stream>>>(Qb, Kb, Vt, Opart, Lpart);

    combine_kernel<<<8192, 256, 0, stream>>>(Opart, Lpart, Ob);

    outproj_kernel<<<dim3(64, 8), 256, 0, stream>>>(Ob, Wo4, out);
}